// Round 9
// baseline (32.248 us; speedup 1.0000x reference)
//
#include <hip/hip_runtime.h>

#define NBATCH 4096
#define NT 2048
#define NP 1024
#define NTH 256
#define EPT 8   // NT elements per thread
#define MSZ 1022          // interior system size (NP-2)
#define KT 4              // conv half-width: |rho|^5 ~ 1.4e-3 rel on M -> ~7e-6 on od
#define IMGW 14           // boundary image reach

// padded LDS index: breaks stride-4 bank patterns (~2-way residual = free)
__device__ __forceinline__ int pQ(int x) { return x + (x >> 3) + 9; }   // x in [-8, 1028]
__device__ __forceinline__ int pM(int x) { return x + (x >> 3); }       // x in [0, 1023]

__global__ __launch_bounds__(NTH, 2) void w2loss_kernel(
    const float* __restrict__ f,
    const float* __restrict__ obs,
    float* __restrict__ partial)
{
    __shared__ float sQp[1168];          // padded q (guard zones may hold garbage; masked)
    __shared__ float sMp[1152];          // padded M
    __shared__ float sH[NTH];            // prev-thread last square handoff
    __shared__ float sPow[IMGW];         // rho^d
    __shared__ float sWSA[4], sWSB[4];
    __shared__ float sSqA[2], sSqB[2];
    __shared__ float sRed[4];

    const int tid  = threadIdx.x;
    const int lane = tid & 63;
    const int wid  = tid >> 6;
    const int b    = blockIdx.x;
    const int base = tid * EPT;

    const float dt      = 0.001f;
    const float half_dt = 0.0005f;
    const float h       = 0.00097751710654936461f;  // 1/1023
    const float inv_h   = 1023.0f;
    const float inv_h2  = 1046529.0f;               // 1023^2
    const float h6      = h * (1.0f / 6.0f);
    const float ih6     = inv_h * (1.0f / 6.0f);

    const float* orow = obs + (size_t)b * NT;
    const float* frow = f   + (size_t)b * NT;
    float4 o0 = *reinterpret_cast<const float4*>(orow + base);
    float4 o1 = *reinterpret_cast<const float4*>(orow + base + 4);
    float4 g0 = *reinterpret_cast<const float4*>(frow + base);
    float4 g1 = *reinterpret_cast<const float4*>(frow + base + 4);

    if (tid < IMGW) {
        const float rho = -0.26794919243112270f;
        float v = 1.0f;
        for (int i = 0; i < tid; ++i) v *= rho;
        sPow[tid] = v;
    }

    // ---- squares + per-thread prefixes for BOTH rows ----
    float prefA[EPT], prefB[EPT];
    {
        float s0;
        s0 = o0.x*o0.x; prefA[0] = s0;
        s0 = o0.y*o0.y; prefA[1] = prefA[0] + s0;
        s0 = o0.z*o0.z; prefA[2] = prefA[1] + s0;
        s0 = o0.w*o0.w; prefA[3] = prefA[2] + s0;
        s0 = o1.x*o1.x; prefA[4] = prefA[3] + s0;
        s0 = o1.y*o1.y; prefA[5] = prefA[4] + s0;
        s0 = o1.z*o1.z; prefA[6] = prefA[5] + s0;
        s0 = o1.w*o1.w; prefA[7] = prefA[6] + s0;
        s0 = g0.x*g0.x; prefB[0] = s0;
        s0 = g0.y*g0.y; prefB[1] = prefB[0] + s0;
        s0 = g0.z*g0.z; prefB[2] = prefB[1] + s0;
        s0 = g0.w*g0.w; prefB[3] = prefB[2] + s0;
        s0 = g1.x*g1.x; prefB[4] = prefB[3] + s0;
        s0 = g1.y*g1.y; prefB[5] = prefB[4] + s0;
        s0 = g1.z*g1.z; prefB[6] = prefB[5] + s0;
        s0 = g1.w*g1.w; prefB[7] = prefB[6] + s0;
    }
    float sqA7 = o1.w * o1.w;
    float sqB7 = g1.w * g1.w;
    sH[tid] = sqA7;                      // handoff BEFORE B1 (read after B1)

    // ---- interleaved wave scans (2x ILP) ----
    float tsA = prefA[EPT - 1], tsB = prefB[EPT - 1];
    float wsA = tsA, wsB = tsB;
#pragma unroll
    for (int off = 1; off < 64; off <<= 1) {
        float uA = __shfl_up(wsA, off);
        float uB = __shfl_up(wsB, off);
        if (lane >= off) { wsA += uA; wsB += uB; }
    }
    if (lane == 63) { sWSA[wid] = wsA; sWSB[wid] = wsB; }
    if (tid == 0)       { sSqA[0] = prefA[0]; sSqB[0] = prefB[0]; }
    if (tid == NTH - 1) { sSqA[1] = sqA7;     sSqB[1] = sqB7; }
    __syncthreads();                                            // B1

    float exclA = wsA - tsA, exclB = wsB - tsB;
    if (wid > 0) { exclA += sWSA[0]; exclB += sWSB[0]; }
    if (wid > 1) { exclA += sWSA[1]; exclB += sWSB[1]; }
    if (wid > 2) { exclA += sWSA[2]; exclB += sWSB[2]; }
    float totA = sWSA[0] + sWSA[1] + sWSA[2] + sWSA[3];
    float totB = sWSB[0] + sWSB[1] + sWSB[2] + sWSB[3];
    float sq0A = sSqA[0], sq0B = sSqB[0];
    float invSA = 1.0f / (half_dt * (2.0f * totA - sSqA[1] - sq0A));
    float invSB = 1.0f / (half_dt * (2.0f * totB - sSqB[1] - sq0B));

    // ---- inverse-CDF by forward scatter: j claims p_k in (c_{j-1}, c_j] ----
    {
        float cm;
        if (tid == 0) cm = -1.0f;
        else {
            float sqprev = sH[tid - 1];
            cm = half_dt * (((exclA - sqprev) + exclA) - sq0A) * invSA;
        }
        float Pm = exclA;
#pragma unroll
        for (int e = 0; e < EPT; ++e) {
            int j = base + e;
            float Pj = exclA + prefA[e];
            float cc = (j == 0) ? 0.0f : half_dt * (Pm + Pj - sq0A) * invSA;
            int kLo = (int)floorf(cm * inv_h) + 1;
            int kHi = (int)floorf(cc * inv_h);
            if (kLo < 0) kLo = 0;
            if (j == NT - 1) kHi = NP - 1;          // guarantee k=1023 coverage
            else {
                if (e == EPT - 1) kHi += 1;         // bridge thread-boundary ulp gap
                if (kHi > NP - 1) kHi = NP - 1;
            }
            float qv = (float)j * dt;
            for (int k = kLo; k <= kHi; ++k) sQp[pQ(k)] = qv;
            cm = cc;
            Pm = Pj;
        }
    }
    __syncthreads();                                            // B2

    // ---- fused stencil: q-window -> rhs (regs, masked) -> M -> sMp ----
    {
        const float Cg = 0.28867513459481288f; // 1/(2*sqrt(3))
        const float CP[KT + 1] = {
            1.0f, -0.26794919243112270f, 0.071796769724490830f,
            -0.019237886466840586f, 0.0051547761428899979f };
        const int k0 = tid * 4;

        float qw[14];
#pragma unroll
        for (int x = 0; x < 14; ++x) qw[x] = sQp[pQ(k0 - 5 + x)];

        float r[12];                     // rhs_{k0-5+x}, zero outside [0, MSZ-1]
#pragma unroll
        for (int x = 0; x < 12; ++x) {
            int gi = k0 - 5 + x;
            float v = 6.0f * (qw[x] - 2.0f * qw[x + 1] + qw[x + 2]) * inv_h2;
            r[x] = (gi >= 0 && gi < MSZ) ? v : 0.0f;
        }

        float T1 = 0.0f, T2 = 0.0f;
        if (tid < 4) {                   // rhs_{0..12} from q[0..14]
            float qe[15];
#pragma unroll
            for (int x = 0; x < 15; ++x) qe[x] = sQp[pQ(x)];
#pragma unroll
            for (int x = 0; x < IMGW - 1; ++x) {
                float rr = 6.0f * (qe[x] - 2.0f * qe[x + 1] + qe[x + 2]) * inv_h2;
                T1 += sPow[x + 1] * rr;
            }
        }
        if (tid >= NTH - 4) {            // rhs_{1009..1021} from q[1009..1023]
            float qe[15];
#pragma unroll
            for (int x = 0; x < 15; ++x) qe[x] = sQp[pQ(1009 + x)];
#pragma unroll
            for (int x = 0; x < IMGW - 1; ++x) {
                float rr = 6.0f * (qe[x] - 2.0f * qe[x + 1] + qe[x + 2]) * inv_h2;
                T2 += sPow[13 - x] * rr;
            }
        }

#pragma unroll
        for (int e = 0; e < 4; ++e) {
            int k = k0 + e;
            float acc = 0.0f;
#pragma unroll
            for (int d = -KT; d <= KT; ++d) {
                int ad = d < 0 ? -d : d;
                acc += CP[ad] * r[e + 4 + d];
            }
            if (k < IMGW)        acc -= sPow[k] * T1;
            if (1023 - k < IMGW) acc -= sPow[1023 - k] * T2;
            float mv = Cg * acc;
            if (k == 0 || k == NP - 1) mv = 0.0f;
            sMp[pM(k)] = mv;
        }
    }
    __syncthreads();                                            // B3

    // ---- Phase B: F in registers, padded gathers, inline coeffs, integrate ----
    float local = 0.0f;
    float term0 = 0.0f, term7 = 0.0f;
    {
        const float c1B = half_dt * invSB;
        const float K0  = (2.0f * exclB - sq0B) * c1B;
        float tj = (float)base * dt;
#pragma unroll
        for (int e = 0; e < EPT; ++e) {
            float Gj = (e ? prefB[e - 1] : 0.0f) + prefB[e];
            float Fj = __builtin_fmaf(Gj, c1B, K0);   // ~exact 0 at j==0
            float sqe = e ? (prefB[e] - prefB[e - 1]) : prefB[0];
            float kf = Fj * inv_h;
            kf = fminf(fmaxf(kf, 0.0f), 1022.0f);
            int k = (int)kf;
            float s = __builtin_fmaf(-h, (float)k, Fj);
            float q0 = sQp[pQ(k)];
            float q1 = sQp[pQ(k + 1)];
            float M0 = sMp[pM(k)];
            float M1 = sMp[pM(k + 1)];
            float bco = (q1 - q0) * inv_h - (2.0f * M0 + M1) * h6;
            float od  = q0 + s * (bco + s * (0.5f * M0 + s * (M1 - M0) * ih6));
            float dd  = tj - od;
            float term = dd * dd * sqe;
            local += term;
            if (e == 0) term0 = term;
            if (e == EPT - 1) term7 = term;
            tj += dt;
        }
    }
    if (tid == 0)       local -= 0.5f * term0;   // trapezoid half-weight at j=0
    if (tid == NTH - 1) local -= 0.5f * term7;   // and at j=NT-1

#pragma unroll
    for (int off = 32; off > 0; off >>= 1) local += __shfl_down(local, off);
    if (lane == 0) sRed[wid] = local;
    __syncthreads();                                            // B4
    if (tid == 0) partial[b] = (sRed[0] + sRed[1] + sRed[2] + sRed[3]) * (dt * invSB);
}

// fixed-order deterministic reduction of 4096 partials -> scalar
__global__ __launch_bounds__(NTH) void w2loss_reduce(
    const float* __restrict__ partial, float* __restrict__ out)
{
    __shared__ float sRed[4];
    const int tid  = threadIdx.x;
    const int lane = tid & 63;
    const int wid  = tid >> 6;
    float s = 0.0f;
#pragma unroll
    for (int i = 0; i < 16; i += 4) {
        float4 v = *reinterpret_cast<const float4*>(partial + tid * 16 + i);
        s += v.x + v.y + v.z + v.w;
    }
#pragma unroll
    for (int off = 32; off > 0; off >>= 1) s += __shfl_down(s, off);
    if (lane == 0) sRed[wid] = s;
    __syncthreads();
    if (tid == 0) out[0] = sRed[0] + sRed[1] + sRed[2] + sRed[3];
}

extern "C" void kernel_launch(void* const* d_in, const int* in_sizes, int n_in,
                              void* d_out, int out_size, void* d_ws, size_t ws_size,
                              hipStream_t stream) {
    const float* f   = (const float*)d_in[0];
    const float* obs = (const float*)d_in[1];
    float* out     = (float*)d_out;
    float* partial = (float*)d_ws;   // 4096 floats = 16 KB scratch

    w2loss_kernel<<<NBATCH, NTH, 0, stream>>>(f, obs, partial);
    w2loss_reduce<<<1, NTH, 0, stream>>>(partial, out);
}